// Round 13
// baseline (1244.033 us; speedup 1.0000x reference)
//
#include <hip/hip_runtime.h>

// FFJORD B=4096 D=64 C=16 H=512, NBIJ=2, NSTEPS=8 RK4 -> 64 sequential MLP+VJP evals.
// Round 19: R18 regressed (988->1058us): hoisting ~12 per-bijector scalars into regs
// overflowed the immovable 64-VGPR allocation -> spilled -> reloaded from SCRATCH every
// eval (FETCH 48->277MB, WRITE 60->106MB). Persistent registers are the scarce resource;
// n-indexed epilogue constants must stay as L2-hot loads (R16 pattern, free).
// This round = R18 structure (cbias, i8 GEMM1 over y, i8 GEMM3f, 320 KB/eval stream)
// with the hoisting reverted: s1/w1t/b2/s2/s3/b3 loaded in epilogues from global.

typedef __attribute__((ext_vector_type(8))) short short8;
typedef __attribute__((ext_vector_type(4))) float f32x4;
typedef __attribute__((ext_vector_type(4))) int int4v;

#define MFMA_B16(a, b, c) __builtin_amdgcn_mfma_f32_16x16x32_bf16((a), (b), (c), 0, 0, 0)
#define MFMA_I8(a, b, c)  __builtin_amdgcn_mfma_i32_16x16x64_i8((a), (b), (c), 0, 0, 0)

__device__ __forceinline__ unsigned short f2bf(float f) {
  union { float f; unsigned u; } v; v.f = f;
  return (unsigned short)((v.u + 0x7FFFu + ((v.u >> 16) & 1u)) >> 16);
}
__device__ __forceinline__ float bf2f(unsigned short u) {
  union { unsigned u; float f; } v; v.u = ((unsigned)u) << 16; return v.f;
}
__device__ __forceinline__ float fast_tanh(float x) {
  float e = __expf(2.f * x);
  return 1.f - 2.f * __builtin_amdgcn_rcpf(e + 1.f);
}

// ws layout (byte offsets):
// W2f8 i8  [2][8p][512n][64k] @ 0       (swizzled granules: k = p*64 + (kk^((n>>1&3)<<4)))
// W1y8 i8  [2][512n][64k]     @ 524288  (W1 rows 0..63, per-col scale s1[n])
// W3f8 i8  [2][64d][512h]     @ 589824  (W3^T, per-col scale s3[d])
// W3b  bf16 [2][512][64]      @ ush 327680 (plain W3: B for e3)
// W1u  bf16 [2][512][64]      @ ush 393216 (W1u[h][d]=W1[d][h]: B for u)
// W1c  bf16 [2][512][32]      @ ush 458752 (W1 rows 64..79, cols padded 16..31=0)
// w1t  f32 [2][512]           @ f32 245760 (W1 row 80)
// s2   f32 [2][512]           @ f32 246784 (colmax |W2[:,n]|)
// s1   f32 [2][512]           @ f32 247808 (colmax |W1[0:64,n]|)
// s3   f32 [2][64]            @ f32 248832 (colmax |W3[:,d]|)

__global__ void prep_scales(const float* __restrict__ W1, const float* __restrict__ W2,
                            const float* __restrict__ W3, float* __restrict__ wsf) {
  int idx = blockIdx.x * 256 + threadIdx.x;
  if (idx < 1024) {
    int ib = idx >> 9, n = idx & 511;
    const float* W = W2 + (size_t)ib * 262144;
    float m = 0.f;
    for (int k = 0; k < 512; ++k) m = fmaxf(m, fabsf(W[(size_t)k * 512 + n]));
    wsf[246784 + idx] = fmaxf(m, 1e-8f);
  } else if (idx < 2048) {
    int i2 = idx - 1024, ib = i2 >> 9, n = i2 & 511;
    const float* W = W1 + (size_t)ib * 41472;
    float m = 0.f;
    for (int k = 0; k < 64; ++k) m = fmaxf(m, fabsf(W[(size_t)k * 512 + n]));
    wsf[247808 + i2] = fmaxf(m, 1e-8f);
  } else if (idx < 2176) {
    int i2 = idx - 2048, ib = i2 >> 6, d = i2 & 63;
    const float* W = W3 + (size_t)ib * 32768;
    float m = 0.f;
    for (int h = 0; h < 512; ++h) m = fmaxf(m, fabsf(W[(size_t)h * 64 + d]));
    wsf[248832 + i2] = fmaxf(m, 1e-8f);
  }
}

__global__ void prep_pack(const float* __restrict__ W1, const float* __restrict__ W2,
                          const float* __restrict__ W3, unsigned short* __restrict__ ws) {
  int o = blockIdx.x * 256 + threadIdx.x;
  char* ws8 = (char*)ws;
  const float* wsf = (const float*)ws;
  if (o < 524288) {
    int ib = o >> 18, b2 = o & 262143;
    int p = b2 >> 15, r2 = b2 & 32767, n = r2 >> 6, kk = r2 & 63;
    int k = p * 64 + (kk ^ (((n >> 1) & 3) << 4));
    float w = W2[(size_t)ib * 262144 + (size_t)k * 512 + n];
    float s = wsf[246784 + ib * 512 + n];
    int q = (int)rintf(w * (127.f / s));
    q = q > 127 ? 127 : (q < -127 ? -127 : q);
    ws8[o] = (char)q;
  } else if (o < 589824) {
    int o2 = o - 524288;
    int ib = o2 >> 15, r = o2 & 32767, n = r >> 6, k = r & 63;
    float w = W1[(size_t)ib * 41472 + (size_t)k * 512 + n];
    float s = wsf[247808 + ib * 512 + n];
    int q = (int)rintf(w * (127.f / s));
    q = q > 127 ? 127 : (q < -127 ? -127 : q);
    ws8[524288 + o2] = (char)q;
  } else if (o < 655360) {
    int o2 = o - 589824;
    int ib = o2 >> 15, r = o2 & 32767, d = r >> 9, h = r & 511;
    float w = W3[(size_t)ib * 32768 + (size_t)h * 64 + d];
    float s = wsf[248832 + ib * 64 + d];
    int q = (int)rintf(w * (127.f / s));
    q = q > 127 ? 127 : (q < -127 ? -127 : q);
    ws8[589824 + o2] = (char)q;
  } else if (o < 720896) {
    int o2 = o - 655360;                     // plain W3 copy [2][512][64]
    ws[327680 + o2] = f2bf(W3[o2]);
  } else if (o < 786432) {
    int o2 = o - 720896;
    int ib = o2 >> 15, r = o2 & 32767, h = r >> 6, d = r & 63;
    ws[393216 + o2] = f2bf(W1[(size_t)ib * 41472 + (size_t)d * 512 + h]);
  } else if (o < 819200) {
    int o2 = o - 786432;
    int ib = o2 >> 14, r = o2 & 16383, n = r >> 5, c = r & 31;
    ws[458752 + o2] = (c < 16) ? f2bf(W1[(size_t)ib * 41472 + (size_t)(64 + c) * 512 + n])
                               : (unsigned short)0;
  } else if (o < 820224) {
    int o2 = o - 819200;
    int ib = o2 >> 9, n = o2 & 511;
    ((float*)ws)[245760 + o2] = W1[(size_t)ib * 41472 + 80 * 512 + n];
  }
}

#define H8 528    // i8 h1/v/h2 buffer stride, bytes
#define INV2 (1.f / 16129.f)   // 1/(127*127)

// Per-wave async stage of one 2KB slice (own 32 rows x 64 bytes) of a 32KB i8 panel.
#define ISSUE_STAGE(WP, KS, BUF) do {                                                   \
    const char* _s = (WP) + (KS) * 32768 + (wave << 11) + (lane << 4);                  \
    char* _d = &Bst[(BUF)][wave << 11];                                                 \
    __builtin_amdgcn_global_load_lds(                                                   \
        (const __attribute__((address_space(1))) void*)_s,                              \
        (__attribute__((address_space(3))) void*)_d, 16, 0, 0);                         \
    __builtin_amdgcn_global_load_lds(                                                   \
        (const __attribute__((address_space(1))) void*)(_s + 1024),                     \
        (__attribute__((address_space(3))) void*)(_d + 1024), 16, 0, 0);                \
  } while (0)

__global__ __launch_bounds__(1024) void ffjord_mfma(
    const float* __restrict__ x, const float* __restrict__ cond, const float* __restrict__ eps,
    const float* __restrict__ b1g, const float* __restrict__ b2g, const float* __restrict__ b3g,
    const unsigned short* __restrict__ ws, float* __restrict__ out) {
  __shared__ __align__(16) char scratch[2 * 16 * H8];  // h1A8 | vA8; prologue: epsA/condA
  __shared__ __align__(16) char h2A8[16 * H8];         // h2 as i8 (q = round(h2*127))
  __shared__ __align__(16) char zA8[16 * 64];          // y as i8 (exact per-row scale)
  __shared__ float cbias[16][512];                     // cond@W1c + b1 (per bijector)
  __shared__ __align__(16) char Bst[3][32768];         // staging ring: 3 x 32KB panels
  __shared__ float f_s[16][64];
  __shared__ float l_row[16], ld_row[16], ldacc[16];
  __shared__ int sgu[16];                              // per-bijector rowmax |u| bits
  __shared__ float sy_s[16];                           // per-eval rowmax |y|

  const int t = threadIdx.x;
  const int wave = t >> 6;
  const int lane = t & 63;
  const int lane15 = lane & 15;
  const int q8 = (lane >> 4) * 8;        // bf16 frag k-offset (ush)
  const int q16 = (lane >> 4) * 16;      // i8 frag k-offset (bytes)
  const int rowb = q8 >> 1;              // C/D row base
  const int row0 = blockIdx.x * 16;
  const int ws32 = wave * 32;            // N-slice base for N=512 GEMMs
  const int nt3 = wave & 3;              // N-tile for GEMM3f
  const int kb3 = (wave >> 2) * 128;     // K-slice byte base for GEMM3f
  const int tm = t >> 6, td = t & 63;
  const int n0 = ws32 + lane15, n1 = n0 + 16;

  const int kk2b = q16 ^ (((lane15 >> 1) & 3) << 4);   // staged-panel read swizzle

  char* h1A8 = scratch;
  char* vA8  = scratch + 16 * H8;

  float ycur, ytmp, yacc = 0.f;
  { float xv = x[(size_t)(row0 + tm) * 64 + td]; ycur = xv; ytmp = xv; }
  if (t < 16) { ld_row[t] = 0.f; l_row[t] = 0.f; }

  const float dt = 0.125f;
  const float w06 = dt / 6.f, w13 = dt / 3.f;
  const char* wsb = (const char*)ws;
  const float* wsf = (const float*)ws;

  for (int ib = 0; ib < 2; ++ib) {
    const char* W2f8 = wsb + ib * 262144;
    const char* W1y8 = wsb + 524288 + ib * 32768;
    const char* W3f8 = wsb + 589824 + ib * 32768;
    const unsigned short* W3b = ws + 327680 + ib * 32768;
    const unsigned short* W1u = ws + 393216 + ib * 32768;
    const unsigned short* W1c = ws + 458752 + ib * 16384;
    const float* w1tg = wsf + 245760 + ib * 512;
    const float* s2g  = wsf + 246784 + ib * 512;
    const float* s1g  = wsf + 247808 + ib * 512;
    const float* s3g  = wsf + 248832 + ib * 64;
    const float* b1b = b1g + ib * 512;
    const float* b2b = b2g + ib * 512;
    const float* b3b = b3g + ib * 64;

    // ---- prologue: stage eps/cond into scratch; e3, u, cbias GEMMs ----
    unsigned short* epsA  = (unsigned short*)scratch;          // [16][72] ush
    unsigned short* condA = (unsigned short*)(scratch + 4096); // [16][32] ush
    epsA[tm * 72 + td] = f2bf(eps[((size_t)ib * 4096 + row0 + tm) * 64 + td]);
    if (t < 512) {
      int m = t >> 5, kk = t & 31;
      condA[m * 32 + kk] = (kk < 16) ? f2bf(cond[(size_t)(row0 + m) * 16 + kk])
                                     : (unsigned short)0;
    }
    if (t < 16) sgu[t] = 0;
    __syncthreads();

    float e3r[8], ur[8];
    {
      f32x4 a0 = {0,0,0,0}, a1 = {0,0,0,0}, u0 = {0,0,0,0}, u1 = {0,0,0,0};
      const unsigned short* ap  = epsA + lane15 * 72 + q8;
      const unsigned short* wp3 = W3b + (size_t)(ws32 + lane15) * 64 + q8;
      const unsigned short* wpu = W1u + (size_t)(ws32 + lane15) * 64 + q8;
      #pragma unroll
      for (int kk = 0; kk < 64; kk += 32) {
        short8 a = *(const short8*)(ap + kk);
        a0 = MFMA_B16(a, *(const short8*)(wp3 + kk),           a0);
        a1 = MFMA_B16(a, *(const short8*)(wp3 + 16 * 64 + kk), a1);
        u0 = MFMA_B16(a, *(const short8*)(wpu + kk),           u0);
        u1 = MFMA_B16(a, *(const short8*)(wpu + 16 * 64 + kk), u1);
      }
      #pragma unroll
      for (int rg = 0; rg < 4; ++rg) {
        e3r[rg] = a0[rg]; e3r[4 + rg] = a1[rg];
        ur[rg] = u0[rg];  ur[4 + rg] = u1[rg];
      }
      #pragma unroll
      for (int rg = 0; rg < 4; ++rg) {
        float mr = fmaxf(fabsf(ur[rg]), fabsf(ur[4 + rg]));
        #pragma unroll
        for (int o = 1; o < 16; o <<= 1) mr = fmaxf(mr, __shfl_xor(mr, o));
        if (lane15 == 0) atomicMax(&sgu[rowb + rg], __float_as_int(mr));
      }
      // cbias = cond @ W1c + b1 (single K=32 bf16 MFMA per tile)
      f32x4 c0 = {0,0,0,0}, c1 = {0,0,0,0};
      short8 ac = *(const short8*)(condA + lane15 * 32 + q8);
      const unsigned short* wpc = W1c + (size_t)(ws32 + lane15) * 32 + q8;
      c0 = MFMA_B16(ac, *(const short8*)wpc,             c0);
      c1 = MFMA_B16(ac, *(const short8*)(wpc + 16 * 32), c1);
      #pragma unroll
      for (int tl = 0; tl < 2; ++tl) {
        int n = tl ? n1 : n0;
        float bb = b1b[n];
        f32x4 cc = tl ? c1 : c0;
        #pragma unroll
        for (int rg = 0; rg < 4; ++rg)
          cbias[rowb + rg][n] = cc[rg] + bb;
      }
    }
    __syncthreads();   // sgu+cbias done; scratch free for h1A8/vA8

    float su_[4], qsv[4];
    #pragma unroll
    for (int rg = 0; rg < 4; ++rg) {
      float sg = fmaxf(__int_as_float(sgu[rowb + rg]), 1e-20f);
      su_[rg] = sg * INV2;
      qsv[rg] = 127.f / sg;
    }

    for (int it = 0; it < 32; ++it) {
      const int s = it & 3;
      const float te = (it >> 2) * dt + ((s == 0) ? 0.f : (s == 3) ? dt : 0.5f * dt);

      // ---- P0: deferred RK4 + logdet; y-quant (exact wave rowmax); zero f_s ----
      if (it > 0) {
        int sp = (it - 1) & 3;
        float fv = f_s[tm][td] + b3b[td];
        if (sp == 0)      { yacc = ycur + w06 * fv; ytmp = ycur + 0.5f * dt * fv; }
        else if (sp == 1) { yacc += w13 * fv;       ytmp = ycur + 0.5f * dt * fv; }
        else if (sp == 2) { yacc += w13 * fv;       ytmp = ycur + dt * fv; }
        else              { float yn = yacc + w06 * fv; ycur = yn; ytmp = yn; }
      }
      f_s[tm][td] = 0.f;
      {
        float my = fabsf(ytmp);
        #pragma unroll
        for (int o = 1; o < 64; o <<= 1) my = fmaxf(my, __shfl_xor(my, o));
        my = fmaxf(my, 1e-20f);
        if (lane == 0) sy_s[tm] = my;
        zA8[tm * 64 + td] = (char)__float2int_rn(ytmp * (127.f / my));
      }
      if (t < 16) {
        if (it > 0) {
          int sp = (it - 1) & 3;
          float lv = l_row[t];
          if (sp == 0)      ldacc[t] = w06 * lv;
          else if (sp < 3)  ldacc[t] += w13 * lv;
          else              ld_row[t] += ldacc[t] + w06 * lv;
        }
        l_row[t] = 0.f;
      }
      if (it == 0) { ISSUE_STAGE(W2f8, 0, 0); ISSUE_STAGE(W2f8, 1, 1); ISSUE_STAGE(W2f8, 2, 2); }
      __syncthreads();

      // ---- P1: i8 GEMM1 (K=64 over y): h1 = tanh(pre + cbias + te*w1t) ----
      {
        int4v a = *(const int4v*)(zA8 + lane15 * 64 + q16);
        int4v b0v = *(const int4v*)(W1y8 + (size_t)n0 * 64 + q16);
        int4v b1v = *(const int4v*)(W1y8 + (size_t)n1 * 64 + q16);
        int4v z4 = {0, 0, 0, 0};
        int4v ac0 = MFMA_I8(a, b0v, z4);
        int4v ac1 = MFMA_I8(a, b1v, z4);
        #pragma unroll
        for (int tl = 0; tl < 2; ++tl) {
          int n = tl ? n1 : n0;
          float t1 = s1g[n] * INV2;      // L2-hot load, NOT a persistent register
          float wt = w1tg[n];
          int4v ac = tl ? ac1 : ac0;
          #pragma unroll
          for (int rg = 0; rg < 4; ++rg) {
            int m = rowb + rg;
            float pre = (float)ac[rg] * (sy_s[m] * t1) + cbias[m][n] + te * wt;
            float th = fast_tanh(pre);
            int off = m * H8 + n;
            h1A8[off] = (char)__float2int_rn(th * 127.f);
            float v = (1.f - th * th) * ur[tl * 4 + rg];
            vA8[off] = (char)__float2int_rn(v * qsv[rg]);
          }
        }
      }
      __syncthreads();

      // ---- P2: staged dual i8 GEMM (h2 + w share B-frags); l in epilogue ----
      {
        int4v ha0 = {0,0,0,0}, ha1 = {0,0,0,0}, wa0 = {0,0,0,0}, wa1 = {0,0,0,0};
        const char* aph = h1A8 + lane15 * H8;
        const char* apv = vA8 + lane15 * H8;
        #pragma unroll
        for (int ks = 0; ks < 8; ++ks) {
          if (ks < 6)       asm volatile("s_waitcnt vmcnt(4)" ::: "memory");
          else if (ks == 6) asm volatile("s_waitcnt vmcnt(2)" ::: "memory");
          else              asm volatile("s_waitcnt vmcnt(0)" ::: "memory");
          const char* bq = &Bst[ks % 3][wave << 11];
          int4v ah = *(const int4v*)(aph + ks * 64 + q16);
          int4v av = *(const int4v*)(apv + ks * 64 + q16);
          int4v b0 = *(const int4v*)(bq + lane15 * 64 + kk2b);
          int4v b1 = *(const int4v*)(bq + (16 + lane15) * 64 + kk2b);
          asm volatile("s_waitcnt lgkmcnt(0)" ::: "memory");
          __builtin_amdgcn_sched_barrier(0);
          if (ks + 3 < 8) { ISSUE_STAGE(W2f8, ks + 3, (ks + 3) % 3); }
          ha0 = MFMA_I8(ah, b0, ha0);
          ha1 = MFMA_I8(ah, b1, ha1);
          wa0 = MFMA_I8(av, b0, wa0);
          wa1 = MFMA_I8(av, b1, wa1);
        }
        float p0 = 0.f, p1 = 0.f, p2 = 0.f, p3 = 0.f;
        #pragma unroll
        for (int tl = 0; tl < 2; ++tl) {
          int n = tl ? n1 : n0;
          float bias = b2b[n];           // L2-hot loads (R16 pattern)
          float s2v = s2g[n];
          float dq = s2v * INV2;
          int4v hac = tl ? ha1 : ha0;
          int4v wac = tl ? wa1 : wa0;
          #pragma unroll
          for (int rg = 0; rg < 4; ++rg) {
            float h = fast_tanh((float)hac[rg] * dq + bias);
            h2A8[(rowb + rg) * H8 + n] = (char)__float2int_rn(h * 127.f);
            float g2 = e3r[tl * 4 + rg] * (1.f - h * h);
            float w = (float)wac[rg] * s2v * su_[rg];
            float pc = g2 * w;
            if (rg == 0) p0 += pc; else if (rg == 1) p1 += pc;
            else if (rg == 2) p2 += pc; else p3 += pc;
          }
        }
        #pragma unroll
        for (int o = 1; o < 16; o <<= 1) {
          p0 += __shfl_xor(p0, o); p1 += __shfl_xor(p1, o);
          p2 += __shfl_xor(p2, o); p3 += __shfl_xor(p3, o);
        }
        if (lane15 == 0) {
          atomicAdd(&l_row[rowb + 0], p0); atomicAdd(&l_row[rowb + 1], p1);
          atomicAdd(&l_row[rowb + 2], p2); atomicAdd(&l_row[rowb + 3], p3);
        }
      }
      __syncthreads();

      // ---- P3: prefetch next-eval panels; i8 GEMM3f: f += h2 @ W3 ----
      if (it < 31) { ISSUE_STAGE(W2f8, 0, 0); ISSUE_STAGE(W2f8, 1, 1); ISSUE_STAGE(W2f8, 2, 2); }
      {
        const char* ap3 = h2A8 + lane15 * H8 + kb3;
        const char* wp3 = W3f8 + (size_t)(nt3 * 16 + lane15) * 512 + kb3;
        float dq3 = s3g[nt3 * 16 + lane15] * INV2;   // L2-hot load per eval
        int4v z4 = {0, 0, 0, 0};
        int4v c = MFMA_I8(*(const int4v*)(ap3 + q16), *(const int4v*)(wp3 + q16), z4);
        c = MFMA_I8(*(const int4v*)(ap3 + 64 + q16), *(const int4v*)(wp3 + 64 + q16), c);
        #pragma unroll
        for (int rg = 0; rg < 4; ++rg)
          atomicAdd(&f_s[rowb + rg][nt3 * 16 + lane15], (float)c[rg] * dq3);
      }
      __syncthreads();
    }

    // ---- bijector finalize: last RK4 stage (s=3) + logdet stage ----
    {
      float fv = f_s[tm][td] + b3b[td];
      float yn = yacc + w06 * fv;
      ycur = yn; ytmp = yn;
    }
    if (t < 16) { ld_row[t] += ldacc[t] + w06 * l_row[t]; l_row[t] = 0.f; }
    __syncthreads();
  }

  out[(size_t)(row0 + tm) * 65 + td] = ycur;
  if (t < 16) out[(size_t)(row0 + t) * 65 + 64] = ld_row[t];
}

extern "C" void kernel_launch(void* const* d_in, const int* in_sizes, int n_in,
                              void* d_out, int out_size, void* d_ws, size_t ws_size,
                              hipStream_t stream) {
  (void)in_sizes; (void)n_in; (void)out_size; (void)ws_size;
  const float* x    = (const float*)d_in[0];
  const float* cond = (const float*)d_in[1];
  const float* eps  = (const float*)d_in[2];
  const float* W1   = (const float*)d_in[3];
  const float* b1   = (const float*)d_in[4];
  const float* W2   = (const float*)d_in[5];
  const float* b2   = (const float*)d_in[6];
  const float* W3   = (const float*)d_in[7];
  const float* b3   = (const float*)d_in[8];
  float* out = (float*)d_out;
  unsigned short* ws = (unsigned short*)d_ws;

  prep_scales<<<9, 256, 0, stream>>>(W1, W2, W3, (float*)ws);
  const int prep_total = 820224;
  prep_pack<<<(prep_total + 255) / 256, 256, 0, stream>>>(W1, W2, W3, ws);
  ffjord_mfma<<<256, 1024, 0, stream>>>(x, cond, eps, b1, b2, b3, ws, out);
}

// Round 14
// 1064.920 us; speedup vs baseline: 1.1682x; 1.1682x over previous
//
#include <hip/hip_runtime.h>

// FFJORD B=4096 D=64 C=16 H=512, NBIJ=2, NSTEPS=8 RK4 -> 64 sequential MLP+VJP evals.
// Round 20: REVERT to the R16 kernel (best verified: 988us dispatch, FETCH 48MB).
// R17/R18/R19 (cbias + i8 GEMM1 + i8 GEMM3f, -96KB/eval) regressed twice with a
// 6-10x FETCH explosion (48 -> 277 -> 457 MB) regardless of whether per-bijector
// scalars were hoisted (R18) or reloaded per eval (R19) -- structure falsified.
// R16's design: time ~ 460us fixed + 1.27us * KB/eval at 416 KB/eval:
//   l = sum(gz*eps) = sum_n g2_n w_n with u = eps@W1y (once/bij), v = (1-h1^2)u,
//   w = v @ W2 riding GEMM2's staged i8 panels (forward orientation; backward
//   stream deleted); g2 stays f32 in regs; RK4+logdet deferred into next P0.
// Eval = 4 phases: P0 | GEMM1 bf16 | dual i8 GEMM2 | GEMM3f bf16.

typedef __attribute__((ext_vector_type(8))) short short8;
typedef __attribute__((ext_vector_type(4))) float f32x4;
typedef __attribute__((ext_vector_type(4))) int int4v;

#define MFMA_B16(a, b, c) __builtin_amdgcn_mfma_f32_16x16x32_bf16((a), (b), (c), 0, 0, 0)
#define MFMA_I8(a, b, c)  __builtin_amdgcn_mfma_i32_16x16x64_i8((a), (b), (c), 0, 0, 0)

__device__ __forceinline__ unsigned short f2bf(float f) {
  union { float f; unsigned u; } v; v.f = f;
  return (unsigned short)((v.u + 0x7FFFu + ((v.u >> 16) & 1u)) >> 16);
}
__device__ __forceinline__ float bf2f(unsigned short u) {
  union { unsigned u; float f; } v; v.u = ((unsigned)u) << 16; return v.f;
}
__device__ __forceinline__ float fast_tanh(float x) {
  float e = __expf(2.f * x);
  return 1.f - 2.f * __builtin_amdgcn_rcpf(e + 1.f);
}

// ws layout:
// W1f  bf16 [2][512][96]       @ ush 0       (k>=81 zero-padded)
// W2f8 i8   [2][8p][512n][64k] @ byte 196608 (W2^T tiles; byte kk stores
//                                             k = p*64 + (kk ^ ((n>>1&3)<<4)))
// W3f  bf16 [2][64][512]       @ ush 360448  (W3^T: B for f = h2 @ W3)
// W3b  bf16 [2][512][64]       @ ush 425984  (plain W3: B for e3 = eps @ W3^T)
// W1u  bf16 [2][512][64]       @ ush 491520  (W1u[h][d] = W1[d][h]: B for u = eps @ W1y)
// sc   f32  [2][512]           @ byte 1114112 (colmax_n |W2[:,n]|)

__global__ void prep_scales(const float* __restrict__ W2, float* __restrict__ sc) {
  int idx = blockIdx.x * 256 + threadIdx.x;
  if (idx >= 1024) return;
  int ib = idx >> 9, n = idx & 511;
  const float* W = W2 + (size_t)ib * 262144;
  float m = 0.f;
  for (int k = 0; k < 512; ++k) m = fmaxf(m, fabsf(W[(size_t)k * 512 + n]));
  sc[idx] = fmaxf(m, 1e-8f);
}

__global__ void prep_bf16(const float* __restrict__ W1, const float* __restrict__ W2,
                          const float* __restrict__ W3, unsigned short* __restrict__ ws) {
  int o = blockIdx.x * 256 + threadIdx.x;
  char* ws8 = (char*)ws;
  const float* sc = (const float*)(ws8 + 1114112);
  if (o < 98304) {
    int ib = o / 49152, r = o % 49152, n = r / 96, k = r % 96;
    ws[o] = (k < 81) ? f2bf(W1[(size_t)ib * 41472 + k * 512 + n]) : (unsigned short)0;
  } else if (o < 622592) {
    int b = o - 98304;
    int ib = b / 262144, b2 = b % 262144;
    int p = b2 / 32768, r2 = b2 % 32768, n = r2 / 64, kk = r2 & 63;
    int k = p * 64 + (kk ^ (((n >> 1) & 3) << 4));
    float w = W2[(size_t)ib * 262144 + (size_t)k * 512 + n];
    float s = sc[ib * 512 + n];
    int q = (int)rintf(w * (127.f / s));
    q = q > 127 ? 127 : (q < -127 ? -127 : q);
    ws8[196608 + b] = (char)q;
  } else if (o < 688128) {
    int o2 = o - 622592;
    int ib = o2 / 32768, r = o2 % 32768, n = r / 512, k = r % 512;
    ws[360448 + o2] = f2bf(W3[(size_t)ib * 32768 + k * 64 + n]);
  } else if (o < 753664) {
    int o2 = o - 688128;
    ws[425984 + o2] = f2bf(W3[o2]);
  } else if (o < 819200) {
    int o2 = o - 753664;
    int ib = o2 / 32768, r = o2 % 32768, h = r / 64, d = r % 64;
    ws[491520 + o2] = f2bf(W1[(size_t)ib * 41472 + d * 512 + h]);
  }
}

#define ZS 104    // z A-buffer stride, ush (K=96 used; also hosts eps for e3/u GEMMs)
#define HS 520    // bf16 h2 buffer stride, ush
#define H8 528    // i8 h1/v buffer stride, bytes
#define INV2 (1.f / 16129.f)   // 1/(127*127)

// Per-wave async stage of one 2KB slice (own 32 rows x 64 bytes) of a 32KB i8 panel.
#define ISSUE_STAGE(WP, KS, BUF) do {                                                   \
    const char* _s = (WP) + (KS) * 32768 + (wave << 11) + (lane << 4);                  \
    char* _d = &Bst[(BUF)][wave << 11];                                                 \
    __builtin_amdgcn_global_load_lds(                                                   \
        (const __attribute__((address_space(1))) void*)_s,                              \
        (__attribute__((address_space(3))) void*)_d, 16, 0, 0);                         \
    __builtin_amdgcn_global_load_lds(                                                   \
        (const __attribute__((address_space(1))) void*)(_s + 1024),                     \
        (__attribute__((address_space(3))) void*)(_d + 1024), 16, 0, 0);                \
  } while (0)

__global__ __launch_bounds__(1024) void ffjord_mfma(
    const float* __restrict__ x, const float* __restrict__ cond, const float* __restrict__ eps,
    const float* __restrict__ b1g, const float* __restrict__ b2g, const float* __restrict__ b3g,
    const unsigned short* __restrict__ ws, float* __restrict__ out) {
  __shared__ unsigned short zA[16 * ZS];
  __shared__ __align__(16) char h1A8[16 * H8];   // h1 as i8 (q = round(h1*127))
  __shared__ __align__(16) char vA8[16 * H8];    // v = (1-h1^2)*u as i8 (scale su[m])
  __shared__ unsigned short h2A[16 * HS];        // h2 bf16 (GEMM3f A-operand)
  __shared__ __align__(16) char Bst[3][32768];   // staging ring: 3 x 32KB i8 panels
  __shared__ float f_s[16][64];
  __shared__ float l_row[16], ld_row[16], ldacc[16];
  __shared__ int sgu[16];                        // per-bijector rowmax |u| bits

  const int t = threadIdx.x;
  const int wave = t >> 6;
  const int lane = t & 63;
  const int lane15 = lane & 15;
  const int q8 = (lane >> 4) * 8;        // bf16 frag k-offset
  const int q16 = (lane >> 4) * 16;      // i8 frag k-offset (bytes)
  const int rowb = q8 >> 1;              // C/D row base
  const int row0 = blockIdx.x * 16;
  const int ws32 = wave * 32;            // N-slice base for N=512 GEMMs
  const int nt3 = wave & 3;              // N-tile for GEMM3f
  const int kb3 = (wave >> 2) * 128;     // K-slice base for GEMM3f
  const int tm = t >> 6, td = t & 63;    // (row, dim) element owned by this thread

  // swizzled 16B-granule read offset (same XOR for rows lane15 and 16+lane15)
  const int kk2b = q16 ^ (((lane15 >> 1) & 3) << 4);

  // RK4 state in registers (thread-private)
  float ycur, ytmp, yacc = 0.f;
  {
    float xv = x[(size_t)(row0 + tm) * 64 + td];
    ycur = xv; ytmp = xv;
  }
  if (t < 512) {
    int m = t >> 5, kk = t & 31;
    zA[m * ZS + 64 + kk] = (kk < 16) ? f2bf(cond[(size_t)(row0 + m) * 16 + kk]) : (unsigned short)0;
  }
  if (t < 16) { ld_row[t] = 0.f; l_row[t] = 0.f; }

  const float dt = 0.125f;
  const float w06 = dt / 6.f, w13 = dt / 3.f;
  const char* wsb = (const char*)ws;

  for (int ib = 0; ib < 2; ++ib) {
    const unsigned short* W1f = ws + ib * 49152;
    const char* W2f8 = wsb + 196608 + ib * 262144;
    const unsigned short* W3f = ws + 360448 + ib * 32768;
    const unsigned short* W3b = ws + 425984 + ib * 32768;
    const unsigned short* W1u = ws + 491520 + ib * 32768;
    const float* scf = (const float*)(wsb + 1114112) + ib * 512;
    const float* b1b = b1g + ib * 512;
    const float* b2b = b2g + ib * 512;
    const float* b3b = b3g + ib * 64;

    // ---- bijector prologue: stage eps (bf16, borrow zA), e3 + u GEMMs ----
    zA[tm * ZS + td] = f2bf(eps[((size_t)ib * 4096 + row0 + tm) * 64 + td]);
    if (t < 16) sgu[t] = 0;
    __syncthreads();

    float e3r[8], ur[8];
    {
      f32x4 a0 = {0,0,0,0}, a1 = {0,0,0,0};   // e3 = eps @ W3^T
      f32x4 u0 = {0,0,0,0}, u1 = {0,0,0,0};   // u  = eps @ W1y
      const unsigned short* ap = zA + lane15 * ZS + q8;
      const unsigned short* wp3 = W3b + (size_t)(ws32 + lane15) * 64 + q8;
      const unsigned short* wpu = W1u + (size_t)(ws32 + lane15) * 64 + q8;
      #pragma unroll
      for (int kk = 0; kk < 64; kk += 32) {
        short8 a = *(const short8*)(ap + kk);
        a0 = MFMA_B16(a, *(const short8*)(wp3 + kk),           a0);
        a1 = MFMA_B16(a, *(const short8*)(wp3 + 16 * 64 + kk), a1);
        u0 = MFMA_B16(a, *(const short8*)(wpu + kk),           u0);
        u1 = MFMA_B16(a, *(const short8*)(wpu + 16 * 64 + kk), u1);
      }
      #pragma unroll
      for (int rg = 0; rg < 4; ++rg) {
        e3r[rg] = a0[rg]; e3r[4 + rg] = a1[rg];
        ur[rg] = u0[rg];  ur[4 + rg] = u1[rg];
      }
      // per-row max|u| (exact per-bijector bound for the v quantization)
      #pragma unroll
      for (int rg = 0; rg < 4; ++rg) {
        float mr = fmaxf(fabsf(ur[rg]), fabsf(ur[4 + rg]));
        #pragma unroll
        for (int o = 1; o < 16; o <<= 1) mr = fmaxf(mr, __shfl_xor(mr, o));
        if (lane15 == 0) atomicMax(&sgu[rowb + rg], __float_as_int(mr));
      }
    }
    __syncthreads();   // sgu complete; zA about to be rewritten by P0

    float su_[4], qsv[4];
    #pragma unroll
    for (int rg = 0; rg < 4; ++rg) {
      float sg = fmaxf(__int_as_float(sgu[rowb + rg]), 1e-20f);
      su_[rg] = sg * INV2;       // folded w-dequant factor (x scf[n] later)
      qsv[rg] = 127.f / sg;
    }

    for (int it = 0; it < 32; ++it) {
      const int s = it & 3;
      const float te = (it >> 2) * dt + ((s == 0) ? 0.f : (s == 3) ? dt : 0.5f * dt);

      // ---- P0: deferred RK4 + logdet, z build, zero f_s; it==0: prefetch panels ----
      if (it > 0) {
        int sp = (it - 1) & 3;
        float fv = f_s[tm][td] + b3b[td];
        if (sp == 0)      { yacc = ycur + w06 * fv; ytmp = ycur + 0.5f * dt * fv; }
        else if (sp == 1) { yacc += w13 * fv;       ytmp = ycur + 0.5f * dt * fv; }
        else if (sp == 2) { yacc += w13 * fv;       ytmp = ycur + dt * fv; }
        else              { float yn = yacc + w06 * fv; ycur = yn; ytmp = yn; }
      }
      zA[tm * ZS + td] = f2bf(ytmp);
      f_s[tm][td] = 0.f;
      if (t < 16) {
        if (it > 0) {
          int sp = (it - 1) & 3;
          float lv = l_row[t];
          if (sp == 0)      ldacc[t] = w06 * lv;
          else if (sp < 3)  ldacc[t] += w13 * lv;
          else              ld_row[t] += ldacc[t] + w06 * lv;
        }
        l_row[t] = 0.f;
        zA[t * ZS + 80] = f2bf(te);
      }
      if (it == 0) { ISSUE_STAGE(W2f8, 0, 0); ISSUE_STAGE(W2f8, 1, 1); ISSUE_STAGE(W2f8, 2, 2); }
      __syncthreads();

      // ---- P1: GEMM1 (bf16): h1 = tanh(z @ W1 + b1); store h1 i8 and v i8 ----
      {
        f32x4 a0 = {0,0,0,0}, a1 = {0,0,0,0};
        const unsigned short* ap = zA + lane15 * ZS + q8;
        const unsigned short* wp = W1f + (size_t)(ws32 + lane15) * 96 + q8;
        #pragma unroll
        for (int k0 = 0; k0 < 96; k0 += 32) {
          short8 a = *(const short8*)(ap + k0);
          a0 = MFMA_B16(a, *(const short8*)(wp + k0),           a0);
          a1 = MFMA_B16(a, *(const short8*)(wp + 16 * 96 + k0), a1);
        }
        #pragma unroll
        for (int tl = 0; tl < 2; ++tl) {
          int n = ws32 + tl * 16 + lane15;
          float bias = b1b[n];
          f32x4 ac = tl ? a1 : a0;
          #pragma unroll
          for (int rg = 0; rg < 4; ++rg) {
            float th = fast_tanh(ac[rg] + bias);
            int off = (rowb + rg) * H8 + n;
            h1A8[off] = (char)__float2int_rn(th * 127.f);
            float v = (1.f - th * th) * ur[tl * 4 + rg];
            vA8[off] = (char)__float2int_rn(v * qsv[rg]);
          }
        }
      }
      __syncthreads();

      // ---- P2: staged dual i8 GEMM (h2-acc and w-acc share B-frags); l in epilogue ----
      {
        int4v ha0 = {0,0,0,0}, ha1 = {0,0,0,0}, wa0 = {0,0,0,0}, wa1 = {0,0,0,0};
        const char* aph = h1A8 + lane15 * H8;
        const char* apv = vA8 + lane15 * H8;
        #pragma unroll
        for (int ks = 0; ks < 8; ++ks) {
          if (ks < 6)       asm volatile("s_waitcnt vmcnt(4)" ::: "memory");
          else if (ks == 6) asm volatile("s_waitcnt vmcnt(2)" ::: "memory");
          else              asm volatile("s_waitcnt vmcnt(0)" ::: "memory");
          const char* bq = &Bst[ks % 3][wave << 11];
          int4v ah = *(const int4v*)(aph + ks * 64 + q16);
          int4v av = *(const int4v*)(apv + ks * 64 + q16);
          int4v b0 = *(const int4v*)(bq + lane15 * 64 + kk2b);
          int4v b1 = *(const int4v*)(bq + (16 + lane15) * 64 + kk2b);
          asm volatile("s_waitcnt lgkmcnt(0)" ::: "memory");
          __builtin_amdgcn_sched_barrier(0);
          if (ks + 3 < 8) { ISSUE_STAGE(W2f8, ks + 3, (ks + 3) % 3); }
          ha0 = MFMA_I8(ah, b0, ha0);
          ha1 = MFMA_I8(ah, b1, ha1);
          wa0 = MFMA_I8(av, b0, wa0);
          wa1 = MFMA_I8(av, b1, wa1);
        }
        float p0 = 0.f, p1 = 0.f, p2 = 0.f, p3 = 0.f;
        #pragma unroll
        for (int tl = 0; tl < 2; ++tl) {
          int n = ws32 + tl * 16 + lane15;
          float bias = b2b[n];
          float dq = scf[n] * INV2;
          float dqw = scf[n];
          int4v hac = tl ? ha1 : ha0;
          int4v wac = tl ? wa1 : wa0;
          #pragma unroll
          for (int rg = 0; rg < 4; ++rg) {
            float h = fast_tanh((float)hac[rg] * dq + bias);
            h2A[(rowb + rg) * HS + n] = f2bf(h);
            float g2 = e3r[tl * 4 + rg] * (1.f - h * h);
            float w = (float)wac[rg] * dqw * su_[rg];
            float pc = g2 * w;
            if (rg == 0) p0 += pc; else if (rg == 1) p1 += pc;
            else if (rg == 2) p2 += pc; else p3 += pc;
          }
        }
        #pragma unroll
        for (int o = 1; o < 16; o <<= 1) {
          p0 += __shfl_xor(p0, o); p1 += __shfl_xor(p1, o);
          p2 += __shfl_xor(p2, o); p3 += __shfl_xor(p3, o);
        }
        if (lane15 == 0) {
          atomicAdd(&l_row[rowb + 0], p0); atomicAdd(&l_row[rowb + 1], p1);
          atomicAdd(&l_row[rowb + 2], p2); atomicAdd(&l_row[rowb + 3], p3);
        }
      }
      __syncthreads();

      // ---- P3: prefetch next-eval panels; GEMM3f (bf16): f += h2 @ W3f ----
      if (it < 31) { ISSUE_STAGE(W2f8, 0, 0); ISSUE_STAGE(W2f8, 1, 1); ISSUE_STAGE(W2f8, 2, 2); }
      {
        f32x4 c0 = {0,0,0,0};
        const unsigned short* ap3 = h2A + lane15 * HS + kb3 + q8;
        const unsigned short* wp3 = W3f + (size_t)(nt3 * 16 + lane15) * 512 + kb3 + q8;
        #pragma unroll
        for (int kk = 0; kk < 128; kk += 32)
          c0 = MFMA_B16(*(const short8*)(ap3 + kk), *(const short8*)(wp3 + kk), c0);
        #pragma unroll
        for (int rg = 0; rg < 4; ++rg)
          atomicAdd(&f_s[rowb + rg][nt3 * 16 + lane15], c0[rg]);
      }
      __syncthreads();
    }

    // ---- bijector finalize: last RK4 stage (s=3) + logdet stage ----
    {
      float fv = f_s[tm][td] + b3b[td];
      float yn = yacc + w06 * fv;
      ycur = yn; ytmp = yn;
    }
    if (t < 16) { ld_row[t] += ldacc[t] + w06 * l_row[t]; l_row[t] = 0.f; }
    __syncthreads();
  }

  out[(size_t)(row0 + tm) * 65 + td] = ycur;
  if (t < 16) out[(size_t)(row0 + t) * 65 + 64] = ld_row[t];
}

extern "C" void kernel_launch(void* const* d_in, const int* in_sizes, int n_in,
                              void* d_out, int out_size, void* d_ws, size_t ws_size,
                              hipStream_t stream) {
  (void)in_sizes; (void)n_in; (void)out_size; (void)ws_size;
  const float* x    = (const float*)d_in[0];
  const float* cond = (const float*)d_in[1];
  const float* eps  = (const float*)d_in[2];
  const float* W1   = (const float*)d_in[3];
  const float* b1   = (const float*)d_in[4];
  const float* W2   = (const float*)d_in[5];
  const float* b2   = (const float*)d_in[6];
  const float* W3   = (const float*)d_in[7];
  const float* b3   = (const float*)d_in[8];
  float* out = (float*)d_out;
  unsigned short* ws = (unsigned short*)d_ws;

  prep_scales<<<4, 256, 0, stream>>>(W2, (float*)((char*)ws + 1114112));
  const int prep_total = 819200;
  prep_bf16<<<(prep_total + 255) / 256, 256, 0, stream>>>(W1, W2, W3, ws);
  ffjord_mfma<<<256, 1024, 0, stream>>>(x, cond, eps, b1, b2, b3, ws, out);
}

// Round 15
// 1037.643 us; speedup vs baseline: 1.1989x; 1.0263x over previous
//
#include <hip/hip_runtime.h>

// FFJORD B=4096 D=64 C=16 H=512, NBIJ=2, NSTEPS=8 RK4 -> 64 sequential MLP+VJP evals.
// Round 21: R20 reproduced the R16 base (977us, FETCH 48MB). No pipe >18% busy ->
// latency-bound. P2's K-loop self-serializes: per-ks lgkmcnt(0)+sched_barrier(0)
// (WAR guard for issuing panel ks+3 into the slot just read) puts LDS latency on the
// critical path 8x per GEMM and blocks compiler pipelining (m141 lesson). Fix:
// delayed-issue ring - prologue 2-deep, at ks issue panel ks+2 into slot (ks-1)%3
// (read LAST iteration). WAR guard becomes lgkmcnt(4) (DS retires in-order: <=4
// outstanding => prior iteration's 4 reads done) ~ free; sched_barrier deleted.
// vmcnt: (2) for ks<7 (panel ks landed; newest pair=p_{ks+1}), (0) at ks=7.
// P0/P3 prefetch 3 -> 2 panels to match. Everything else identical to R20.

typedef __attribute__((ext_vector_type(8))) short short8;
typedef __attribute__((ext_vector_type(4))) float f32x4;
typedef __attribute__((ext_vector_type(4))) int int4v;

#define MFMA_B16(a, b, c) __builtin_amdgcn_mfma_f32_16x16x32_bf16((a), (b), (c), 0, 0, 0)
#define MFMA_I8(a, b, c)  __builtin_amdgcn_mfma_i32_16x16x64_i8((a), (b), (c), 0, 0, 0)

__device__ __forceinline__ unsigned short f2bf(float f) {
  union { float f; unsigned u; } v; v.f = f;
  return (unsigned short)((v.u + 0x7FFFu + ((v.u >> 16) & 1u)) >> 16);
}
__device__ __forceinline__ float bf2f(unsigned short u) {
  union { unsigned u; float f; } v; v.u = ((unsigned)u) << 16; return v.f;
}
__device__ __forceinline__ float fast_tanh(float x) {
  float e = __expf(2.f * x);
  return 1.f - 2.f * __builtin_amdgcn_rcpf(e + 1.f);
}

// ws layout:
// W1f  bf16 [2][512][96]       @ ush 0       (k>=81 zero-padded)
// W2f8 i8   [2][8p][512n][64k] @ byte 196608 (W2^T tiles; byte kk stores
//                                             k = p*64 + (kk ^ ((n>>1&3)<<4)))
// W3f  bf16 [2][64][512]       @ ush 360448  (W3^T: B for f = h2 @ W3)
// W3b  bf16 [2][512][64]       @ ush 425984  (plain W3: B for e3 = eps @ W3^T)
// W1u  bf16 [2][512][64]       @ ush 491520  (W1u[h][d] = W1[d][h]: B for u = eps @ W1y)
// sc   f32  [2][512]           @ byte 1114112 (colmax_n |W2[:,n]|)

__global__ void prep_scales(const float* __restrict__ W2, float* __restrict__ sc) {
  int idx = blockIdx.x * 256 + threadIdx.x;
  if (idx >= 1024) return;
  int ib = idx >> 9, n = idx & 511;
  const float* W = W2 + (size_t)ib * 262144;
  float m = 0.f;
  for (int k = 0; k < 512; ++k) m = fmaxf(m, fabsf(W[(size_t)k * 512 + n]));
  sc[idx] = fmaxf(m, 1e-8f);
}

__global__ void prep_bf16(const float* __restrict__ W1, const float* __restrict__ W2,
                          const float* __restrict__ W3, unsigned short* __restrict__ ws) {
  int o = blockIdx.x * 256 + threadIdx.x;
  char* ws8 = (char*)ws;
  const float* sc = (const float*)(ws8 + 1114112);
  if (o < 98304) {
    int ib = o / 49152, r = o % 49152, n = r / 96, k = r % 96;
    ws[o] = (k < 81) ? f2bf(W1[(size_t)ib * 41472 + k * 512 + n]) : (unsigned short)0;
  } else if (o < 622592) {
    int b = o - 98304;
    int ib = b / 262144, b2 = b % 262144;
    int p = b2 / 32768, r2 = b2 % 32768, n = r2 / 64, kk = r2 & 63;
    int k = p * 64 + (kk ^ (((n >> 1) & 3) << 4));
    float w = W2[(size_t)ib * 262144 + (size_t)k * 512 + n];
    float s = sc[ib * 512 + n];
    int q = (int)rintf(w * (127.f / s));
    q = q > 127 ? 127 : (q < -127 ? -127 : q);
    ws8[196608 + b] = (char)q;
  } else if (o < 688128) {
    int o2 = o - 622592;
    int ib = o2 / 32768, r = o2 % 32768, n = r / 512, k = r % 512;
    ws[360448 + o2] = f2bf(W3[(size_t)ib * 32768 + k * 64 + n]);
  } else if (o < 753664) {
    int o2 = o - 688128;
    ws[425984 + o2] = f2bf(W3[o2]);
  } else if (o < 819200) {
    int o2 = o - 753664;
    int ib = o2 / 32768, r = o2 % 32768, h = r / 64, d = r % 64;
    ws[491520 + o2] = f2bf(W1[(size_t)ib * 41472 + d * 512 + h]);
  }
}

#define ZS 104    // z A-buffer stride, ush (K=96 used; also hosts eps for e3/u GEMMs)
#define HS 520    // bf16 h2 buffer stride, ush
#define H8 528    // i8 h1/v buffer stride, bytes
#define INV2 (1.f / 16129.f)   // 1/(127*127)

// Per-wave async stage of one 2KB slice (own 32 rows x 64 bytes) of a 32KB i8 panel.
#define ISSUE_STAGE(WP, KS, BUF) do {                                                   \
    const char* _s = (WP) + (KS) * 32768 + (wave << 11) + (lane << 4);                  \
    char* _d = &Bst[(BUF)][wave << 11];                                                 \
    __builtin_amdgcn_global_load_lds(                                                   \
        (const __attribute__((address_space(1))) void*)_s,                              \
        (__attribute__((address_space(3))) void*)_d, 16, 0, 0);                         \
    __builtin_amdgcn_global_load_lds(                                                   \
        (const __attribute__((address_space(1))) void*)(_s + 1024),                     \
        (__attribute__((address_space(3))) void*)(_d + 1024), 16, 0, 0);                \
  } while (0)

__global__ __launch_bounds__(1024) void ffjord_mfma(
    const float* __restrict__ x, const float* __restrict__ cond, const float* __restrict__ eps,
    const float* __restrict__ b1g, const float* __restrict__ b2g, const float* __restrict__ b3g,
    const unsigned short* __restrict__ ws, float* __restrict__ out) {
  __shared__ unsigned short zA[16 * ZS];
  __shared__ __align__(16) char h1A8[16 * H8];   // h1 as i8 (q = round(h1*127))
  __shared__ __align__(16) char vA8[16 * H8];    // v = (1-h1^2)*u as i8 (scale su[m])
  __shared__ unsigned short h2A[16 * HS];        // h2 bf16 (GEMM3f A-operand)
  __shared__ __align__(16) char Bst[3][32768];   // staging ring: 3 x 32KB i8 panels
  __shared__ float f_s[16][64];
  __shared__ float l_row[16], ld_row[16], ldacc[16];
  __shared__ int sgu[16];                        // per-bijector rowmax |u| bits

  const int t = threadIdx.x;
  const int wave = t >> 6;
  const int lane = t & 63;
  const int lane15 = lane & 15;
  const int q8 = (lane >> 4) * 8;        // bf16 frag k-offset
  const int q16 = (lane >> 4) * 16;      // i8 frag k-offset (bytes)
  const int rowb = q8 >> 1;              // C/D row base
  const int row0 = blockIdx.x * 16;
  const int ws32 = wave * 32;            // N-slice base for N=512 GEMMs
  const int nt3 = wave & 3;              // N-tile for GEMM3f
  const int kb3 = (wave >> 2) * 128;     // K-slice base for GEMM3f
  const int tm = t >> 6, td = t & 63;    // (row, dim) element owned by this thread

  // swizzled 16B-granule read offset (same XOR for rows lane15 and 16+lane15)
  const int kk2b = q16 ^ (((lane15 >> 1) & 3) << 4);

  // RK4 state in registers (thread-private)
  float ycur, ytmp, yacc = 0.f;
  {
    float xv = x[(size_t)(row0 + tm) * 64 + td];
    ycur = xv; ytmp = xv;
  }
  if (t < 512) {
    int m = t >> 5, kk = t & 31;
    zA[m * ZS + 64 + kk] = (kk < 16) ? f2bf(cond[(size_t)(row0 + m) * 16 + kk]) : (unsigned short)0;
  }
  if (t < 16) { ld_row[t] = 0.f; l_row[t] = 0.f; }

  const float dt = 0.125f;
  const float w06 = dt / 6.f, w13 = dt / 3.f;
  const char* wsb = (const char*)ws;

  for (int ib = 0; ib < 2; ++ib) {
    const unsigned short* W1f = ws + ib * 49152;
    const char* W2f8 = wsb + 196608 + ib * 262144;
    const unsigned short* W3f = ws + 360448 + ib * 32768;
    const unsigned short* W3b = ws + 425984 + ib * 32768;
    const unsigned short* W1u = ws + 491520 + ib * 32768;
    const float* scf = (const float*)(wsb + 1114112) + ib * 512;
    const float* b1b = b1g + ib * 512;
    const float* b2b = b2g + ib * 512;
    const float* b3b = b3g + ib * 64;

    // ---- bijector prologue: stage eps (bf16, borrow zA), e3 + u GEMMs ----
    zA[tm * ZS + td] = f2bf(eps[((size_t)ib * 4096 + row0 + tm) * 64 + td]);
    if (t < 16) sgu[t] = 0;
    __syncthreads();

    float e3r[8], ur[8];
    {
      f32x4 a0 = {0,0,0,0}, a1 = {0,0,0,0};   // e3 = eps @ W3^T
      f32x4 u0 = {0,0,0,0}, u1 = {0,0,0,0};   // u  = eps @ W1y
      const unsigned short* ap = zA + lane15 * ZS + q8;
      const unsigned short* wp3 = W3b + (size_t)(ws32 + lane15) * 64 + q8;
      const unsigned short* wpu = W1u + (size_t)(ws32 + lane15) * 64 + q8;
      #pragma unroll
      for (int kk = 0; kk < 64; kk += 32) {
        short8 a = *(const short8*)(ap + kk);
        a0 = MFMA_B16(a, *(const short8*)(wp3 + kk),           a0);
        a1 = MFMA_B16(a, *(const short8*)(wp3 + 16 * 64 + kk), a1);
        u0 = MFMA_B16(a, *(const short8*)(wpu + kk),           u0);
        u1 = MFMA_B16(a, *(const short8*)(wpu + 16 * 64 + kk), u1);
      }
      #pragma unroll
      for (int rg = 0; rg < 4; ++rg) {
        e3r[rg] = a0[rg]; e3r[4 + rg] = a1[rg];
        ur[rg] = u0[rg];  ur[4 + rg] = u1[rg];
      }
      // per-row max|u| (exact per-bijector bound for the v quantization)
      #pragma unroll
      for (int rg = 0; rg < 4; ++rg) {
        float mr = fmaxf(fabsf(ur[rg]), fabsf(ur[4 + rg]));
        #pragma unroll
        for (int o = 1; o < 16; o <<= 1) mr = fmaxf(mr, __shfl_xor(mr, o));
        if (lane15 == 0) atomicMax(&sgu[rowb + rg], __float_as_int(mr));
      }
    }
    __syncthreads();   // sgu complete; zA about to be rewritten by P0

    float su_[4], qsv[4];
    #pragma unroll
    for (int rg = 0; rg < 4; ++rg) {
      float sg = fmaxf(__int_as_float(sgu[rowb + rg]), 1e-20f);
      su_[rg] = sg * INV2;       // folded w-dequant factor (x scf[n] later)
      qsv[rg] = 127.f / sg;
    }

    for (int it = 0; it < 32; ++it) {
      const int s = it & 3;
      const float te = (it >> 2) * dt + ((s == 0) ? 0.f : (s == 3) ? dt : 0.5f * dt);

      // ---- P0: deferred RK4 + logdet, z build, zero f_s; it==0: prefetch 2 panels ----
      if (it > 0) {
        int sp = (it - 1) & 3;
        float fv = f_s[tm][td] + b3b[td];
        if (sp == 0)      { yacc = ycur + w06 * fv; ytmp = ycur + 0.5f * dt * fv; }
        else if (sp == 1) { yacc += w13 * fv;       ytmp = ycur + 0.5f * dt * fv; }
        else if (sp == 2) { yacc += w13 * fv;       ytmp = ycur + dt * fv; }
        else              { float yn = yacc + w06 * fv; ycur = yn; ytmp = yn; }
      }
      zA[tm * ZS + td] = f2bf(ytmp);
      f_s[tm][td] = 0.f;
      if (t < 16) {
        if (it > 0) {
          int sp = (it - 1) & 3;
          float lv = l_row[t];
          if (sp == 0)      ldacc[t] = w06 * lv;
          else if (sp < 3)  ldacc[t] += w13 * lv;
          else              ld_row[t] += ldacc[t] + w06 * lv;
        }
        l_row[t] = 0.f;
        zA[t * ZS + 80] = f2bf(te);
      }
      if (it == 0) { ISSUE_STAGE(W2f8, 0, 0); ISSUE_STAGE(W2f8, 1, 1); }
      __syncthreads();

      // ---- P1: GEMM1 (bf16): h1 = tanh(z @ W1 + b1); store h1 i8 and v i8 ----
      {
        f32x4 a0 = {0,0,0,0}, a1 = {0,0,0,0};
        const unsigned short* ap = zA + lane15 * ZS + q8;
        const unsigned short* wp = W1f + (size_t)(ws32 + lane15) * 96 + q8;
        #pragma unroll
        for (int k0 = 0; k0 < 96; k0 += 32) {
          short8 a = *(const short8*)(ap + k0);
          a0 = MFMA_B16(a, *(const short8*)(wp + k0),           a0);
          a1 = MFMA_B16(a, *(const short8*)(wp + 16 * 96 + k0), a1);
        }
        #pragma unroll
        for (int tl = 0; tl < 2; ++tl) {
          int n = ws32 + tl * 16 + lane15;
          float bias = b1b[n];
          f32x4 ac = tl ? a1 : a0;
          #pragma unroll
          for (int rg = 0; rg < 4; ++rg) {
            float th = fast_tanh(ac[rg] + bias);
            int off = (rowb + rg) * H8 + n;
            h1A8[off] = (char)__float2int_rn(th * 127.f);
            float v = (1.f - th * th) * ur[tl * 4 + rg];
            vA8[off] = (char)__float2int_rn(v * qsv[rg]);
          }
        }
      }
      __syncthreads();

      // ---- P2: staged dual i8 GEMM, delayed-issue ring (no order-pinning) ----
      {
        int4v ha0 = {0,0,0,0}, ha1 = {0,0,0,0}, wa0 = {0,0,0,0}, wa1 = {0,0,0,0};
        const char* aph = h1A8 + lane15 * H8;
        const char* apv = vA8 + lane15 * H8;
        #pragma unroll
        for (int ks = 0; ks < 8; ++ks) {
          // wait panel ks landed: newest pair in flight is p_{ks+1}; at ks=7 drain all
          if (ks < 7) asm volatile("s_waitcnt vmcnt(2)" ::: "memory");
          else        asm volatile("s_waitcnt vmcnt(0)" ::: "memory");
          const char* bq = &Bst[ks % 3][wave << 11];
          int4v ah = *(const int4v*)(aph + ks * 64 + q16);
          int4v av = *(const int4v*)(apv + ks * 64 + q16);
          int4v b0 = *(const int4v*)(bq + lane15 * 64 + kk2b);
          int4v b1 = *(const int4v*)(bq + (16 + lane15) * 64 + kk2b);
          if (ks < 6) {
            // WAR guard: slot (ks+2)%3 == (ks-1)%3 was read LAST iteration; DS retires
            // in-order, so lgkmcnt(4) (this iteration's 4 reads may remain) suffices.
            asm volatile("s_waitcnt lgkmcnt(4)" ::: "memory");
            ISSUE_STAGE(W2f8, ks + 2, (ks + 2) % 3);
          }
          ha0 = MFMA_I8(ah, b0, ha0);
          ha1 = MFMA_I8(ah, b1, ha1);
          wa0 = MFMA_I8(av, b0, wa0);
          wa1 = MFMA_I8(av, b1, wa1);
        }
        float p0 = 0.f, p1 = 0.f, p2 = 0.f, p3 = 0.f;
        #pragma unroll
        for (int tl = 0; tl < 2; ++tl) {
          int n = ws32 + tl * 16 + lane15;
          float bias = b2b[n];
          float dq = scf[n] * INV2;
          float dqw = scf[n];
          int4v hac = tl ? ha1 : ha0;
          int4v wac = tl ? wa1 : wa0;
          #pragma unroll
          for (int rg = 0; rg < 4; ++rg) {
            float h = fast_tanh((float)hac[rg] * dq + bias);
            h2A[(rowb + rg) * HS + n] = f2bf(h);
            float g2 = e3r[tl * 4 + rg] * (1.f - h * h);
            float w = (float)wac[rg] * dqw * su_[rg];
            float pc = g2 * w;
            if (rg == 0) p0 += pc; else if (rg == 1) p1 += pc;
            else if (rg == 2) p2 += pc; else p3 += pc;
          }
        }
        #pragma unroll
        for (int o = 1; o < 16; o <<= 1) {
          p0 += __shfl_xor(p0, o); p1 += __shfl_xor(p1, o);
          p2 += __shfl_xor(p2, o); p3 += __shfl_xor(p3, o);
        }
        if (lane15 == 0) {
          atomicAdd(&l_row[rowb + 0], p0); atomicAdd(&l_row[rowb + 1], p1);
          atomicAdd(&l_row[rowb + 2], p2); atomicAdd(&l_row[rowb + 3], p3);
        }
      }
      __syncthreads();

      // ---- P3: prefetch next-eval panels 0,1; GEMM3f (bf16): f += h2 @ W3f ----
      if (it < 31) { ISSUE_STAGE(W2f8, 0, 0); ISSUE_STAGE(W2f8, 1, 1); }
      {
        f32x4 c0 = {0,0,0,0};
        const unsigned short* ap3 = h2A + lane15 * HS + kb3 + q8;
        const unsigned short* wp3 = W3f + (size_t)(nt3 * 16 + lane15) * 512 + kb3 + q8;
        #pragma unroll
        for (int kk = 0; kk < 128; kk += 32)
          c0 = MFMA_B16(*(const short8*)(ap3 + kk), *(const short8*)(wp3 + kk), c0);
        #pragma unroll
        for (int rg = 0; rg < 4; ++rg)
          atomicAdd(&f_s[rowb + rg][nt3 * 16 + lane15], c0[rg]);
      }
      __syncthreads();
    }

    // ---- bijector finalize: last RK4 stage (s=3) + logdet stage ----
    {
      float fv = f_s[tm][td] + b3b[td];
      float yn = yacc + w06 * fv;
      ycur = yn; ytmp = yn;
    }
    if (t < 16) { ld_row[t] += ldacc[t] + w06 * l_row[t]; l_row[t] = 0.f; }
    __syncthreads();
  }

  out[(size_t)(row0 + tm) * 65 + td] = ycur;
  if (t < 16) out[(size_t)(row0 + t) * 65 + 64] = ld_row[t];
}

extern "C" void kernel_launch(void* const* d_in, const int* in_sizes, int n_in,
                              void* d_out, int out_size, void* d_ws, size_t ws_size,
                              hipStream_t stream) {
  (void)in_sizes; (void)n_in; (void)out_size; (void)ws_size;
  const float* x    = (const float*)d_in[0];
  const float* cond = (const float*)d_in[1];
  const float* eps  = (const float*)d_in[2];
  const float* W1   = (const float*)d_in[3];
  const float* b1   = (const float*)d_in[4];
  const float* W2   = (const float*)d_in[5];
  const float* b2   = (const float*)d_in[6];
  const float* W3   = (const float*)d_in[7];
  const float* b3   = (const float*)d_in[8];
  float* out = (float*)d_out;
  unsigned short* ws = (unsigned short*)d_ws;

  prep_scales<<<4, 256, 0, stream>>>(W2, (float*)((char*)ws + 1114112));
  const int prep_total = 819200;
  prep_bf16<<<(prep_total + 255) / 256, 256, 0, stream>>>(W1, W2, W3, ws);
  ffjord_mfma<<<256, 1024, 0, stream>>>(x, cond, eps, b1, b2, b3, ws, out);
}